// Round 1
// baseline (1486.679 us; speedup 1.0000x reference)
//
#include <hip/hip_runtime.h>

#define B_  2
#define S_  2048
#define D_  4096
#define H_  16
#define HD_ 256
#define N1  12288
#define N2  4096

typedef __attribute__((ext_vector_type(8))) short  bf8_t;   // 8 bf16 (4 VGPRs)
typedef __attribute__((ext_vector_type(8))) ushort us8_t;
typedef __attribute__((ext_vector_type(4))) float  f4_t;

__device__ __forceinline__ ushort f2bf(float f) {
  union { float f; uint u; } c; c.f = f;
  uint u = c.u;
  return (ushort)((u + 0x7fffu + ((u >> 16) & 1u)) >> 16);  // RNE
}
__device__ __forceinline__ float bf2f(ushort b) {
  union { uint u; float f; } c; c.u = ((uint)b) << 16;
  return c.f;
}

#define MFMA16(a, b, c) __builtin_amdgcn_mfma_f32_16x16x32_bf16((a), (b), (c), 0, 0, 0)

// ---------------------------------------------------------------------------
// GEMM1: qkv = hidden(f32) @ dequant(Wqkv) ; scatter q,k,v -> (B,H,S,hd) bf16
// ---------------------------------------------------------------------------
__global__ __launch_bounds__(256) void gemm_qkv(
    const float* __restrict__ hid, const int* __restrict__ qw,
    const int* __restrict__ qz, const float* __restrict__ sc,
    ushort* __restrict__ wq, ushort* __restrict__ wk, ushort* __restrict__ wv)
{
  __shared__ ushort As[128][72];  // [m][k], +8 pad
  __shared__ ushort Bs[128][72];  // [n][k], +8 pad
  const int tid  = threadIdx.x;
  const int lane = tid & 63, wave = tid >> 6;
  const int quad = lane >> 4, l15 = lane & 15;
  const int n0 = blockIdx.x * 128, m0 = blockIdx.y * 128;

  f4_t acc[4][4];
#pragma unroll
  for (int i = 0; i < 4; ++i)
#pragma unroll
    for (int j = 0; j < 4; ++j) acc[i][j] = (f4_t){0.f, 0.f, 0.f, 0.f};

  const int bn  = tid & 127;   // B-staging column within tile
  const int brh = tid >> 7;    // 0/1 -> qweight row halves
  const int gn  = n0 + bn;
  const int wm = (wave >> 1) * 64, wn = (wave & 1) * 64;

  for (int k0 = 0; k0 < D_; k0 += 64) {
    // stage A: 128 x 64 f32 -> bf16
#pragma unroll
    for (int i = 0; i < 8; ++i) {
      const int u = tid + 256 * i;
      const int m = u >> 4, kc = u & 15;
      const float4 v = *(const float4*)(hid + (size_t)(m0 + m) * D_ + k0 + kc * 4);
      ushort4 b;
      b.x = f2bf(v.x); b.y = f2bf(v.y); b.z = f2bf(v.z); b.w = f2bf(v.w);
      *(ushort4*)(&As[m][kc * 4]) = b;
    }
    // stage B: dequant 64 x 128 -> bf16, stored transposed [n][k]
    {
      const int g = k0 >> 7;                      // GS=128 group
      const int zw = qz[g * (N1 / 8) + (gn >> 3)];
      const float zp = (float)(((zw >> ((gn & 7) * 4)) & 15) + 1);
      const float scale = sc[g * N1 + gn];
      const float szp = scale * zp;
      const int kq0 = (k0 >> 3) + brh * 4;
#pragma unroll
      for (int i = 0; i < 4; ++i) {
        const uint w = (uint)qw[(size_t)(kq0 + i) * N1 + gn];
        us8_t pk;
#pragma unroll
        for (int j = 0; j < 8; ++j)
          pk[j] = f2bf(fmaf((float)((w >> (4 * j)) & 15u), scale, -szp));
        *(us8_t*)(&Bs[bn][(brh * 4 + i) * 8]) = pk;
      }
    }
    __syncthreads();
#pragma unroll
    for (int kk = 0; kk < 64; kk += 32) {
      bf8_t af[4], bfv[4];
#pragma unroll
      for (int i = 0; i < 4; ++i)
        af[i] = *(const bf8_t*)(&As[wm + i * 16 + l15][kk + quad * 8]);
#pragma unroll
      for (int j = 0; j < 4; ++j)
        bfv[j] = *(const bf8_t*)(&Bs[wn + j * 16 + l15][kk + quad * 8]);
#pragma unroll
      for (int i = 0; i < 4; ++i)
#pragma unroll
        for (int j = 0; j < 4; ++j)
          acc[i][j] = MFMA16(af[i], bfv[j], acc[i][j]);
    }
    __syncthreads();
  }

  // epilogue: scatter to (which, B, H, S, hd) bf16
  const int which = n0 >> 12;
  const int nh = (n0 & 4095) >> 8;
  const int d0 = n0 & 255;           // 0 or 128
  const int bb = m0 >> 11;
  const int s_base = m0 & 2047;
  ushort* dst = (which == 0) ? wq : (which == 1) ? wk : wv;
  const size_t rowbase = ((size_t)bb * H_ + nh) * S_;
#pragma unroll
  for (int i = 0; i < 4; ++i) {
#pragma unroll
    for (int r = 0; r < 4; ++r) {
      const int s = s_base + wm + i * 16 + quad * 4 + r;
      ushort* prow = dst + (rowbase + s) * HD_ + d0 + wn + l15;
#pragma unroll
      for (int j = 0; j < 4; ++j)
        prow[j * 16] = f2bf(acc[i][j][r]);
    }
  }
}

// ---------------------------------------------------------------------------
// RoPE in-place on q and k: first 64 dims, GPT-J rotate-every-two
// ---------------------------------------------------------------------------
__global__ __launch_bounds__(256) void rope_qk(ushort* __restrict__ q, ushort* __restrict__ k)
{
  const int idx = blockIdx.x * 256 + threadIdx.x;   // 2^22 threads
  const int i   = idx & 31;                         // pair index (dims 2i,2i+1)
  const int row = (idx >> 5) & 0xFFFF;              // (b*H+h)*S + s
  const int buf = idx >> 21;
  const int s   = row & 2047;
  ushort* p = (buf ? k : q) + (size_t)row * HD_ + 2 * i;
  // inv_freq = 10000^(-2i/64) = exp(-2i * ln(10000)/64)
  const float inv_freq = expf((float)(2 * i) * -0.14391157f);
  const float ang = (float)s * inv_freq;
  float sn, cs;
  sincosf(ang, &sn, &cs);
  uint pr = *(uint*)p;
  const float x1 = bf2f((ushort)(pr & 0xFFFF));
  const float x2 = bf2f((ushort)(pr >> 16));
  const uint lo = f2bf(x1 * cs - x2 * sn);
  const uint hi = f2bf(x2 * cs + x1 * sn);
  *(uint*)p = lo | (hi << 16);
}

// ---------------------------------------------------------------------------
// V (B,H,S,hd) -> VT (B,H,hd,S)
// ---------------------------------------------------------------------------
__global__ __launch_bounds__(256) void transpose_v(const ushort* __restrict__ v,
                                                   ushort* __restrict__ vt)
{
  __shared__ uint t32[64][65];
  const int tid = threadIdx.x;
  const int s0 = blockIdx.x * 64, d0 = blockIdx.y * 64, bh = blockIdx.z;
  const ushort* src = v + ((size_t)bh * S_ + s0) * HD_ + d0;
#pragma unroll
  for (int i = 0; i < 2; ++i) {
    const int u = tid + 256 * i;
    const int r = u >> 3, cu = u & 7;
    const uint4 val = *(const uint4*)(src + (size_t)r * HD_ + cu * 8);
    const ushort* pv = (const ushort*)&val;
#pragma unroll
    for (int j = 0; j < 8; ++j) t32[r][cu * 8 + j] = pv[j];
  }
  __syncthreads();
  ushort* dstb = vt + ((size_t)bh * HD_ + d0) * S_ + s0;
#pragma unroll
  for (int i = 0; i < 2; ++i) {
    const int u = tid + 256 * i;
    const int dr = u >> 3, cu = u & 7;
    union { ushort u16[8]; uint4 v4; } tmp;
#pragma unroll
    for (int j = 0; j < 8; ++j) tmp.u16[j] = (ushort)t32[cu * 8 + j][dr];
    *(uint4*)(dstb + (size_t)dr * S_ + cu * 8) = tmp.v4;
  }
}

// ---------------------------------------------------------------------------
// Flash attention: per (b,h) and 64-row q tile; 4 waves x 16 q-rows
// ---------------------------------------------------------------------------
__global__ __launch_bounds__(256) void flash_attn(
    const ushort* __restrict__ Q, const ushort* __restrict__ K,
    const ushort* __restrict__ VT, ushort* __restrict__ attn)
{
  __shared__ ushort Kls[32][264];      // [key][d] +8 pad
  __shared__ ushort Vls[256][40];      // [d][key] +8 pad (from VT)
  __shared__ ushort Pls[4][16][40];    // per-wave P roundtrip
  const int tid  = threadIdx.x;
  const int lane = tid & 63, wave = tid >> 6;
  const int quad = lane >> 4, l15 = lane & 15;
  const int qt = 31 - blockIdx.x;      // heavy (large-qt) blocks first
  const int bh = blockIdx.y;

  const ushort* qb = Q + ((size_t)bh * S_ + qt * 64 + wave * 16 + l15) * HD_;
  bf8_t qf[8];
#pragma unroll
  for (int c = 0; c < 8; ++c)
    qf[c] = *(const bf8_t*)(qb + c * 32 + quad * 8);

  f4_t o[16];
#pragma unroll
  for (int i = 0; i < 16; ++i) o[i] = (f4_t){0.f, 0.f, 0.f, 0.f};
  float m_r[4] = {-1e30f, -1e30f, -1e30f, -1e30f};
  float l_r[4] = {0.f, 0.f, 0.f, 0.f};

  const int qrow0 = qt * 64 + wave * 16 + quad * 4;
  const int nkt = 2 * (qt + 1);
  const ushort* kb0 = K + (size_t)bh * S_ * HD_;
  const ushort* vb0 = VT + (size_t)bh * HD_ * S_;

  for (int kt = 0; kt < nkt; ++kt) {
    __syncthreads();   // protect LDS from previous iteration's readers
#pragma unroll
    for (int i = 0; i < 4; ++i) {      // K tile 32x256
      const int u = tid + 256 * i;
      const int r = u >> 5, cu = u & 31;
      *(uint4*)(&Kls[r][cu * 8]) =
          *(const uint4*)(kb0 + (size_t)(kt * 32 + r) * HD_ + cu * 8);
    }
#pragma unroll
    for (int i = 0; i < 4; ++i) {      // VT tile 256x32
      const int u = tid + 256 * i;
      const int d = u >> 2, cu = u & 3;
      *(uint4*)(&Vls[d][cu * 8]) =
          *(const uint4*)(vb0 + (size_t)d * S_ + kt * 32 + cu * 8);
    }
    __syncthreads();

    // S = Q K^T : 16 x 32
    f4_t sf[2];
    sf[0] = (f4_t){0.f, 0.f, 0.f, 0.f};
    sf[1] = (f4_t){0.f, 0.f, 0.f, 0.f};
#pragma unroll
    for (int c = 0; c < 8; ++c) {
      const bf8_t b0 = *(const bf8_t*)(&Kls[l15][c * 32 + quad * 8]);
      const bf8_t b1 = *(const bf8_t*)(&Kls[16 + l15][c * 32 + quad * 8]);
      sf[0] = MFMA16(qf[c], b0, sf[0]);
      sf[1] = MFMA16(qf[c], b1, sf[1]);
    }

    // mask + scale + online softmax
    const int key0 = kt * 32;
    float mt[4];
#pragma unroll
    for (int r = 0; r < 4; ++r) {
      const int qr = qrow0 + r;
#pragma unroll
      for (int f = 0; f < 2; ++f) {
        const int key = key0 + f * 16 + l15;
        const float sv = sf[f][r] * 0.0625f;   // 1/sqrt(256)
        sf[f][r] = (key <= qr) ? sv : -1e30f;
      }
      mt[r] = fmaxf(sf[0][r], sf[1][r]);
    }
#pragma unroll
    for (int off = 1; off < 16; off <<= 1)
#pragma unroll
      for (int r = 0; r < 4; ++r)
        mt[r] = fmaxf(mt[r], __shfl_xor(mt[r], off));
    float alpha[4], rs[4];
#pragma unroll
    for (int r = 0; r < 4; ++r) {
      const float mn = fmaxf(m_r[r], mt[r]);
      alpha[r] = __expf(m_r[r] - mn);
      m_r[r] = mn;
      const float p0 = __expf(sf[0][r] - mn);
      const float p1 = __expf(sf[1][r] - mn);
      sf[0][r] = p0; sf[1][r] = p1;
      rs[r] = p0 + p1;
    }
#pragma unroll
    for (int off = 1; off < 16; off <<= 1)
#pragma unroll
      for (int r = 0; r < 4; ++r)
        rs[r] += __shfl_xor(rs[r], off);
#pragma unroll
    for (int r = 0; r < 4; ++r)
      l_r[r] = l_r[r] * alpha[r] + rs[r];
#pragma unroll
    for (int i = 0; i < 16; ++i)
#pragma unroll
      for (int r = 0; r < 4; ++r)
        o[i][r] *= alpha[r];

    // P (C-layout) -> LDS -> A-layout; wave-private, DS in-order per wave
#pragma unroll
    for (int f = 0; f < 2; ++f)
#pragma unroll
      for (int r = 0; r < 4; ++r)
        Pls[wave][quad * 4 + r][f * 16 + l15] = f2bf(sf[f][r]);
    const bf8_t ap = *(const bf8_t*)(&Pls[wave][l15][quad * 8]);

    // O += P V
#pragma unroll
    for (int df = 0; df < 16; ++df) {
      const bf8_t bv = *(const bf8_t*)(&Vls[df * 16 + l15][quad * 8]);
      o[df] = MFMA16(ap, bv, o[df]);
    }
  }

  // epilogue: attn (B,S,D) bf16
  const int b = bh >> 4, h = bh & 15;
  float inv[4];
#pragma unroll
  for (int r = 0; r < 4; ++r) inv[r] = 1.0f / l_r[r];
#pragma unroll
  for (int r = 0; r < 4; ++r) {
    const int s = qt * 64 + wave * 16 + quad * 4 + r;
    ushort* prow = attn + ((size_t)b * S_ + s) * D_ + h * HD_ + l15;
#pragma unroll
    for (int df = 0; df < 16; ++df)
      prow[df * 16] = f2bf(o[df][r] * inv[r]);
  }
}

// ---------------------------------------------------------------------------
// GEMM2: out = attn(bf16) @ dequant(Wout) -> f32
// ---------------------------------------------------------------------------
__global__ __launch_bounds__(256) void gemm_out(
    const ushort* __restrict__ attn, const int* __restrict__ qw,
    const int* __restrict__ qz, const float* __restrict__ sc,
    float* __restrict__ out)
{
  __shared__ ushort As[128][72];
  __shared__ ushort Bs[128][72];
  const int tid  = threadIdx.x;
  const int lane = tid & 63, wave = tid >> 6;
  const int quad = lane >> 4, l15 = lane & 15;
  const int n0 = blockIdx.x * 128, m0 = blockIdx.y * 128;

  f4_t acc[4][4];
#pragma unroll
  for (int i = 0; i < 4; ++i)
#pragma unroll
    for (int j = 0; j < 4; ++j) acc[i][j] = (f4_t){0.f, 0.f, 0.f, 0.f};

  const int bn  = tid & 127;
  const int brh = tid >> 7;
  const int gn  = n0 + bn;
  const int wm = (wave >> 1) * 64, wn = (wave & 1) * 64;

  for (int k0 = 0; k0 < D_; k0 += 64) {
#pragma unroll
    for (int i = 0; i < 4; ++i) {   // stage A: bf16 direct 16B copies
      const int u = tid + 256 * i;
      const int m = u >> 3, kc = u & 7;
      *(uint4*)(&As[m][kc * 8]) =
          *(const uint4*)(attn + (size_t)(m0 + m) * D_ + k0 + kc * 8);
    }
    {
      const int g = k0 >> 7;
      const int zw = qz[g * (N2 / 8) + (gn >> 3)];
      const float zp = (float)(((zw >> ((gn & 7) * 4)) & 15) + 1);
      const float scale = sc[g * N2 + gn];
      const float szp = scale * zp;
      const int kq0 = (k0 >> 3) + brh * 4;
#pragma unroll
      for (int i = 0; i < 4; ++i) {
        const uint w = (uint)qw[(size_t)(kq0 + i) * N2 + gn];
        us8_t pk;
#pragma unroll
        for (int j = 0; j < 8; ++j)
          pk[j] = f2bf(fmaf((float)((w >> (4 * j)) & 15u), scale, -szp));
        *(us8_t*)(&Bs[bn][(brh * 4 + i) * 8]) = pk;
      }
    }
    __syncthreads();
#pragma unroll
    for (int kk = 0; kk < 64; kk += 32) {
      bf8_t af[4], bfv[4];
#pragma unroll
      for (int i = 0; i < 4; ++i)
        af[i] = *(const bf8_t*)(&As[wm + i * 16 + l15][kk + quad * 8]);
#pragma unroll
      for (int j = 0; j < 4; ++j)
        bfv[j] = *(const bf8_t*)(&Bs[wn + j * 16 + l15][kk + quad * 8]);
#pragma unroll
      for (int i = 0; i < 4; ++i)
#pragma unroll
        for (int j = 0; j < 4; ++j)
          acc[i][j] = MFMA16(af[i], bfv[j], acc[i][j]);
    }
    __syncthreads();
  }
#pragma unroll
  for (int i = 0; i < 4; ++i) {
#pragma unroll
    for (int r = 0; r < 4; ++r) {
      float* prow = out + (size_t)(m0 + wm + i * 16 + quad * 4 + r) * D_ + n0 + wn + l15;
#pragma unroll
      for (int j = 0; j < 4; ++j)
        prow[j * 16] = acc[i][j][r];
    }
  }
}

// ---------------------------------------------------------------------------
extern "C" void kernel_launch(void* const* d_in, const int* in_sizes, int n_in,
                              void* d_out, int out_size, void* d_ws, size_t ws_size,
                              hipStream_t stream)
{
  const float* hid    = (const float*)d_in[0];
  const int*   qw_qkv = (const int*)d_in[1];
  const int*   qz_qkv = (const int*)d_in[2];
  const float* sc_qkv = (const float*)d_in[3];
  const int*   qw_out = (const int*)d_in[4];
  const int*   qz_out = (const int*)d_in[5];
  const float* sc_out = (const float*)d_in[6];
  float* out = (float*)d_out;

  const size_t QKV_E = (size_t)B_ * H_ * S_ * HD_;   // 16,777,216 elems
  ushort* wsq    = (ushort*)d_ws;
  ushort* wsk    = wsq + QKV_E;
  ushort* wsv    = wsk + QKV_E;
  ushort* wsvt   = wsv + QKV_E;
  ushort* wsattn = wsvt + QKV_E;                     // total 167.8 MB

  gemm_qkv<<<dim3(96, 32), 256, 0, stream>>>(hid, qw_qkv, qz_qkv, sc_qkv, wsq, wsk, wsv);
  rope_qk<<<dim3(16384), 256, 0, stream>>>(wsq, wsk);
  transpose_v<<<dim3(32, 4, 32), 256, 0, stream>>>(wsv, wsvt);
  flash_attn<<<dim3(32, 32), 256, 0, stream>>>(wsq, wsk, wsvt, wsattn);
  gemm_out<<<dim3(32, 32), 256, 0, stream>>>(wsattn, qw_out, qz_out, sc_out, out);
}

// Round 2
// 1203.134 us; speedup vs baseline: 1.2357x; 1.2357x over previous
//
#include <hip/hip_runtime.h>

#define B_  2
#define S_  2048
#define D_  4096
#define H_  16
#define HD_ 256
#define N1  12288
#define N2  4096

typedef __attribute__((ext_vector_type(8))) short  bf8_t;   // 8 bf16 (4 VGPRs)
typedef __attribute__((ext_vector_type(8))) ushort us8_t;
typedef __attribute__((ext_vector_type(4))) float  f4_t;

__device__ __forceinline__ ushort f2bf(float f) {
  union { float f; uint u; } c; c.f = f;
  uint u = c.u;
  return (ushort)((u + 0x7fffu + ((u >> 16) & 1u)) >> 16);  // RNE
}
__device__ __forceinline__ float bf2f(ushort b) {
  union { uint u; float f; } c; c.u = ((uint)b) << 16;
  return c.f;
}

#define MFMA16(a, b, c) __builtin_amdgcn_mfma_f32_16x16x32_bf16((a), (b), (c), 0, 0, 0)

__device__ __forceinline__ void gload16(const void* g, void* l) {
  __builtin_amdgcn_global_load_lds(
      (const __attribute__((address_space(1))) void*)g,
      (__attribute__((address_space(3))) void*)l, 16, 0, 0);
}

// ---------------------------------------------------------------------------
// hidden f32 -> bf16
// ---------------------------------------------------------------------------
__global__ __launch_bounds__(256) void cvt_bf16(const float* __restrict__ x,
                                                ushort* __restrict__ y)
{
  const size_t i = ((size_t)blockIdx.x * 256 + threadIdx.x) * 8;
  const float4 a = *(const float4*)(x + i);
  const float4 b = *(const float4*)(x + i + 4);
  us8_t o;
  o[0] = f2bf(a.x); o[1] = f2bf(a.y); o[2] = f2bf(a.z); o[3] = f2bf(a.w);
  o[4] = f2bf(b.x); o[5] = f2bf(b.y); o[6] = f2bf(b.z); o[7] = f2bf(b.w);
  *(us8_t*)(y + i) = o;
}

// ---------------------------------------------------------------------------
// GPTQ dequant -> W^T bf16 [N][4096]  (one-shot, memory-bound)
// ---------------------------------------------------------------------------
__global__ __launch_bounds__(256) void dequant_w(
    const int* __restrict__ qw, const int* __restrict__ qz,
    const float* __restrict__ sc, ushort* __restrict__ wt, const int N)
{
  __shared__ ushort T[64][72];
  const int tid = threadIdx.x;
  const int n0 = blockIdx.x * 64, k0 = blockIdx.y * 64;
  const int g = k0 >> 7;                           // GS=128
  const int nn  = tid & 63;
  const int kw0 = tid >> 6;                        // 0..3
  const int gn = n0 + nn;
  const int zw = qz[g * (N >> 3) + (gn >> 3)];
  const float zp = (float)(((zw >> ((gn & 7) * 4)) & 15) + 1);
  const float scale = sc[g * N + gn];
  const float szp = scale * zp;
#pragma unroll
  for (int t = 0; t < 2; ++t) {
    const int kw = kw0 + t * 4;
    const uint w = (uint)qw[(size_t)((k0 >> 3) + kw) * N + gn];
    us8_t pk;
#pragma unroll
    for (int j = 0; j < 8; ++j)
      pk[j] = f2bf(fmaf((float)((w >> (4 * j)) & 15u), scale, -szp));
    *(us8_t*)(&T[nn][kw * 8]) = pk;
  }
  __syncthreads();
#pragma unroll
  for (int t = 0; t < 2; ++t) {
    const int u = tid + t * 256;
    const int r = u >> 3, c = u & 7;
    *(uint4*)(wt + (size_t)(n0 + r) * 4096 + k0 + c * 8) = *(uint4*)(&T[r][c * 8]);
  }
}

// ---------------------------------------------------------------------------
// Fast bf16 GEMM core (m97 structure): A[M][4096] bf16, BT[N][4096] bf16.
// global_load_lds w=16 staging with XOR swizzle; 128x128 tile, BK=64.
// ---------------------------------------------------------------------------
#define GEMM_CORE(A_, BT_)                                                    \
  __shared__ ushort As[8192];                                                 \
  __shared__ ushort Bs[8192];                                                 \
  const int tid  = threadIdx.x;                                               \
  const int lane = tid & 63, wave = tid >> 6;                                 \
  const int quad = lane >> 4, l15 = lane & 15;                                \
  const int n0 = blockIdx.x * 128, m0 = blockIdx.y * 128;                     \
  const int wm = (wave >> 1) * 64, wn = (wave & 1) * 64;                      \
  f4_t acc[4][4];                                                             \
  _Pragma("unroll") for (int i = 0; i < 4; ++i)                               \
  _Pragma("unroll") for (int j = 0; j < 4; ++j)                               \
      acc[i][j] = (f4_t){0.f, 0.f, 0.f, 0.f};                                 \
  const int r_in_c = lane >> 3;                                               \
  const int qc_x   = lane & 7;                                                \
  for (int k0 = 0; k0 < 4096; k0 += 64) {                                     \
    __syncthreads();                                                          \
    _Pragma("unroll") for (int i = 0; i < 4; ++i) {                           \
      const int c = wave * 4 + i;                                             \
      const int row = c * 8 + r_in_c;                                         \
      const int qc  = qc_x ^ (row & 7);                                       \
      gload16(A_ + (size_t)(m0 + row) * 4096 + k0 + qc * 8, &As[c * 512]);    \
      gload16(BT_ + (size_t)(n0 + row) * 4096 + k0 + qc * 8, &Bs[c * 512]);   \
    }                                                                         \
    __syncthreads();                                                          \
    _Pragma("unroll") for (int kk = 0; kk < 2; ++kk) {                        \
      bf8_t af[4], bfv[4];                                                    \
      _Pragma("unroll") for (int i = 0; i < 4; ++i) {                         \
        const int row = wm + i * 16 + l15;                                    \
        const int ch  = (kk * 4 + quad) ^ (row & 7);                          \
        af[i] = *(const bf8_t*)(&As[row * 64 + ch * 8]);                      \
      }                                                                       \
      _Pragma("unroll") for (int j = 0; j < 4; ++j) {                         \
        const int col = wn + j * 16 + l15;                                    \
        const int ch  = (kk * 4 + quad) ^ (col & 7);                          \
        bfv[j] = *(const bf8_t*)(&Bs[col * 64 + ch * 8]);                     \
      }                                                                       \
      _Pragma("unroll") for (int i = 0; i < 4; ++i)                           \
      _Pragma("unroll") for (int j = 0; j < 4; ++j)                           \
          acc[i][j] = MFMA16(af[i], bfv[j], acc[i][j]);                       \
    }                                                                         \
  }

__global__ __launch_bounds__(256) void gemm_fast_qkv(
    const ushort* __restrict__ A, const ushort* __restrict__ BT,
    ushort* __restrict__ wq, ushort* __restrict__ wk, ushort* __restrict__ wv)
{
  GEMM_CORE(A, BT)
  // epilogue: scatter to (which, B, H, S, hd) bf16
  const int which = n0 >> 12;
  const int nh = (n0 & 4095) >> 8;
  const int d0 = n0 & 255;
  const int bb = m0 >> 11;
  const int s_base = m0 & 2047;
  ushort* dst = (which == 0) ? wq : (which == 1) ? wk : wv;
  const size_t rowbase = ((size_t)bb * H_ + nh) * S_;
#pragma unroll
  for (int i = 0; i < 4; ++i) {
#pragma unroll
    for (int r = 0; r < 4; ++r) {
      const int s = s_base + wm + i * 16 + quad * 4 + r;
      ushort* prow = dst + (rowbase + s) * HD_ + d0 + wn + l15;
#pragma unroll
      for (int j = 0; j < 4; ++j)
        prow[j * 16] = f2bf(acc[i][j][r]);
    }
  }
}

__global__ __launch_bounds__(256) void gemm_fast_out(
    const ushort* __restrict__ A, const ushort* __restrict__ BT,
    float* __restrict__ out)
{
  GEMM_CORE(A, BT)
#pragma unroll
  for (int i = 0; i < 4; ++i) {
#pragma unroll
    for (int r = 0; r < 4; ++r) {
      float* prow = out + (size_t)(m0 + wm + i * 16 + quad * 4 + r) * D_ + n0 + wn + l15;
#pragma unroll
      for (int j = 0; j < 4; ++j)
        prow[j * 16] = acc[i][j][r];
    }
  }
}

// ---------------------------------------------------------------------------
// FALLBACK (round-1 validated): dequant-in-GEMM
// ---------------------------------------------------------------------------
__global__ __launch_bounds__(256) void gemm_qkv_fb(
    const float* __restrict__ hid, const int* __restrict__ qw,
    const int* __restrict__ qz, const float* __restrict__ sc,
    ushort* __restrict__ wq, ushort* __restrict__ wk, ushort* __restrict__ wv)
{
  __shared__ ushort As[128][72];
  __shared__ ushort Bs[128][72];
  const int tid  = threadIdx.x;
  const int lane = tid & 63, wave = tid >> 6;
  const int quad = lane >> 4, l15 = lane & 15;
  const int n0 = blockIdx.x * 128, m0 = blockIdx.y * 128;
  f4_t acc[4][4];
#pragma unroll
  for (int i = 0; i < 4; ++i)
#pragma unroll
    for (int j = 0; j < 4; ++j) acc[i][j] = (f4_t){0.f, 0.f, 0.f, 0.f};
  const int bn  = tid & 127;
  const int brh = tid >> 7;
  const int gn  = n0 + bn;
  const int wm = (wave >> 1) * 64, wn = (wave & 1) * 64;
  for (int k0 = 0; k0 < D_; k0 += 64) {
#pragma unroll
    for (int i = 0; i < 8; ++i) {
      const int u = tid + 256 * i;
      const int m = u >> 4, kc = u & 15;
      const float4 v = *(const float4*)(hid + (size_t)(m0 + m) * D_ + k0 + kc * 4);
      ushort4 b;
      b.x = f2bf(v.x); b.y = f2bf(v.y); b.z = f2bf(v.z); b.w = f2bf(v.w);
      *(ushort4*)(&As[m][kc * 4]) = b;
    }
    {
      const int g = k0 >> 7;
      const int zw = qz[g * (N1 / 8) + (gn >> 3)];
      const float zp = (float)(((zw >> ((gn & 7) * 4)) & 15) + 1);
      const float scale = sc[g * N1 + gn];
      const float szp = scale * zp;
      const int kq0 = (k0 >> 3) + brh * 4;
#pragma unroll
      for (int i = 0; i < 4; ++i) {
        const uint w = (uint)qw[(size_t)(kq0 + i) * N1 + gn];
        us8_t pk;
#pragma unroll
        for (int j = 0; j < 8; ++j)
          pk[j] = f2bf(fmaf((float)((w >> (4 * j)) & 15u), scale, -szp));
        *(us8_t*)(&Bs[bn][(brh * 4 + i) * 8]) = pk;
      }
    }
    __syncthreads();
#pragma unroll
    for (int kk = 0; kk < 64; kk += 32) {
      bf8_t af[4], bfv[4];
#pragma unroll
      for (int i = 0; i < 4; ++i)
        af[i] = *(const bf8_t*)(&As[wm + i * 16 + l15][kk + quad * 8]);
#pragma unroll
      for (int j = 0; j < 4; ++j)
        bfv[j] = *(const bf8_t*)(&Bs[wn + j * 16 + l15][kk + quad * 8]);
#pragma unroll
      for (int i = 0; i < 4; ++i)
#pragma unroll
        for (int j = 0; j < 4; ++j)
          acc[i][j] = MFMA16(af[i], bfv[j], acc[i][j]);
    }
    __syncthreads();
  }
  const int which = n0 >> 12;
  const int nh = (n0 & 4095) >> 8;
  const int d0 = n0 & 255;
  const int bb = m0 >> 11;
  const int s_base = m0 & 2047;
  ushort* dst = (which == 0) ? wq : (which == 1) ? wk : wv;
  const size_t rowbase = ((size_t)bb * H_ + nh) * S_;
#pragma unroll
  for (int i = 0; i < 4; ++i) {
#pragma unroll
    for (int r = 0; r < 4; ++r) {
      const int s = s_base + wm + i * 16 + quad * 4 + r;
      ushort* prow = dst + (rowbase + s) * HD_ + d0 + wn + l15;
#pragma unroll
      for (int j = 0; j < 4; ++j)
        prow[j * 16] = f2bf(acc[i][j][r]);
    }
  }
}

__global__ __launch_bounds__(256) void gemm_out_fb(
    const ushort* __restrict__ attn, const int* __restrict__ qw,
    const int* __restrict__ qz, const float* __restrict__ sc,
    float* __restrict__ out)
{
  __shared__ ushort As[128][72];
  __shared__ ushort Bs[128][72];
  const int tid  = threadIdx.x;
  const int lane = tid & 63, wave = tid >> 6;
  const int quad = lane >> 4, l15 = lane & 15;
  const int n0 = blockIdx.x * 128, m0 = blockIdx.y * 128;
  f4_t acc[4][4];
#pragma unroll
  for (int i = 0; i < 4; ++i)
#pragma unroll
    for (int j = 0; j < 4; ++j) acc[i][j] = (f4_t){0.f, 0.f, 0.f, 0.f};
  const int bn  = tid & 127;
  const int brh = tid >> 7;
  const int gn  = n0 + bn;
  const int wm = (wave >> 1) * 64, wn = (wave & 1) * 64;
  for (int k0 = 0; k0 < D_; k0 += 64) {
#pragma unroll
    for (int i = 0; i < 4; ++i) {
      const int u = tid + 256 * i;
      const int m = u >> 3, kc = u & 7;
      *(uint4*)(&As[m][kc * 8]) =
          *(const uint4*)(attn + (size_t)(m0 + m) * D_ + k0 + kc * 8);
    }
    {
      const int g = k0 >> 7;
      const int zw = qz[g * (N2 / 8) + (gn >> 3)];
      const float zp = (float)(((zw >> ((gn & 7) * 4)) & 15) + 1);
      const float scale = sc[g * N2 + gn];
      const float szp = scale * zp;
      const int kq0 = (k0 >> 3) + brh * 4;
#pragma unroll
      for (int i = 0; i < 4; ++i) {
        const uint w = (uint)qw[(size_t)(kq0 + i) * N2 + gn];
        us8_t pk;
#pragma unroll
        for (int j = 0; j < 8; ++j)
          pk[j] = f2bf(fmaf((float)((w >> (4 * j)) & 15u), scale, -szp));
        *(us8_t*)(&Bs[bn][(brh * 4 + i) * 8]) = pk;
      }
    }
    __syncthreads();
#pragma unroll
    for (int kk = 0; kk < 64; kk += 32) {
      bf8_t af[4], bfv[4];
#pragma unroll
      for (int i = 0; i < 4; ++i)
        af[i] = *(const bf8_t*)(&As[wm + i * 16 + l15][kk + quad * 8]);
#pragma unroll
      for (int j = 0; j < 4; ++j)
        bfv[j] = *(const bf8_t*)(&Bs[wn + j * 16 + l15][kk + quad * 8]);
#pragma unroll
      for (int i = 0; i < 4; ++i)
#pragma unroll
        for (int j = 0; j < 4; ++j)
          acc[i][j] = MFMA16(af[i], bfv[j], acc[i][j]);
    }
    __syncthreads();
  }
#pragma unroll
  for (int i = 0; i < 4; ++i) {
#pragma unroll
    for (int r = 0; r < 4; ++r) {
      float* prow = out + (size_t)(m0 + wm + i * 16 + quad * 4 + r) * D_ + n0 + wn + l15;
#pragma unroll
      for (int j = 0; j < 4; ++j)
        prow[j * 16] = acc[i][j][r];
    }
  }
}

// ---------------------------------------------------------------------------
// RoPE in-place on q and k
// ---------------------------------------------------------------------------
__global__ __launch_bounds__(256) void rope_qk(ushort* __restrict__ q, ushort* __restrict__ k)
{
  const int idx = blockIdx.x * 256 + threadIdx.x;
  const int i   = idx & 31;
  const int row = (idx >> 5) & 0xFFFF;
  const int buf = idx >> 21;
  const int s   = row & 2047;
  ushort* p = (buf ? k : q) + (size_t)row * HD_ + 2 * i;
  const float inv_freq = expf((float)(2 * i) * -0.14391157f);
  const float ang = (float)s * inv_freq;
  float sn, cs;
  sincosf(ang, &sn, &cs);
  uint pr = *(uint*)p;
  const float x1 = bf2f((ushort)(pr & 0xFFFF));
  const float x2 = bf2f((ushort)(pr >> 16));
  const uint lo = f2bf(x1 * cs - x2 * sn);
  const uint hi = f2bf(x2 * cs + x1 * sn);
  *(uint*)p = lo | (hi << 16);
}

// ---------------------------------------------------------------------------
// V (B,H,S,hd) -> VT (B,H,hd,S)
// ---------------------------------------------------------------------------
__global__ __launch_bounds__(256) void transpose_v(const ushort* __restrict__ v,
                                                   ushort* __restrict__ vt)
{
  __shared__ uint t32[64][65];
  const int tid = threadIdx.x;
  const int s0 = blockIdx.x * 64, d0 = blockIdx.y * 64, bh = blockIdx.z;
  const ushort* src = v + ((size_t)bh * S_ + s0) * HD_ + d0;
#pragma unroll
  for (int i = 0; i < 2; ++i) {
    const int u = tid + 256 * i;
    const int r = u >> 3, cu = u & 7;
    const uint4 val = *(const uint4*)(src + (size_t)r * HD_ + cu * 8);
    const ushort* pv = (const ushort*)&val;
#pragma unroll
    for (int j = 0; j < 8; ++j) t32[r][cu * 8 + j] = pv[j];
  }
  __syncthreads();
  ushort* dstb = vt + ((size_t)bh * HD_ + d0) * S_ + s0;
#pragma unroll
  for (int i = 0; i < 2; ++i) {
    const int u = tid + 256 * i;
    const int dr = u >> 3, cu = u & 7;
    union { ushort u16[8]; uint4 v4; } tmp;
#pragma unroll
    for (int j = 0; j < 8; ++j) tmp.u16[j] = (ushort)t32[cu * 8 + j][dr];
    *(uint4*)(dstb + (size_t)dr * S_ + cu * 8) = tmp.v4;
  }
}

// ---------------------------------------------------------------------------
// Flash attention: per (b,h) and 64-row q tile
// ---------------------------------------------------------------------------
__global__ __launch_bounds__(256) void flash_attn(
    const ushort* __restrict__ Q, const ushort* __restrict__ K,
    const ushort* __restrict__ VT, ushort* __restrict__ attn)
{
  __shared__ ushort Kls[32][264];
  __shared__ ushort Vls[256][40];
  __shared__ ushort Pls[4][16][40];
  const int tid  = threadIdx.x;
  const int lane = tid & 63, wave = tid >> 6;
  const int quad = lane >> 4, l15 = lane & 15;
  const int qt = 31 - blockIdx.x;
  const int bh = blockIdx.y;

  const ushort* qb = Q + ((size_t)bh * S_ + qt * 64 + wave * 16 + l15) * HD_;
  bf8_t qf[8];
#pragma unroll
  for (int c = 0; c < 8; ++c)
    qf[c] = *(const bf8_t*)(qb + c * 32 + quad * 8);

  f4_t o[16];
#pragma unroll
  for (int i = 0; i < 16; ++i) o[i] = (f4_t){0.f, 0.f, 0.f, 0.f};
  float m_r[4] = {-1e30f, -1e30f, -1e30f, -1e30f};
  float l_r[4] = {0.f, 0.f, 0.f, 0.f};

  const int qrow0 = qt * 64 + wave * 16 + quad * 4;
  const int nkt = 2 * (qt + 1);
  const ushort* kb0 = K + (size_t)bh * S_ * HD_;
  const ushort* vb0 = VT + (size_t)bh * HD_ * S_;

  for (int kt = 0; kt < nkt; ++kt) {
    __syncthreads();
#pragma unroll
    for (int i = 0; i < 4; ++i) {
      const int u = tid + 256 * i;
      const int r = u >> 5, cu = u & 31;
      *(uint4*)(&Kls[r][cu * 8]) =
          *(const uint4*)(kb0 + (size_t)(kt * 32 + r) * HD_ + cu * 8);
    }
#pragma unroll
    for (int i = 0; i < 4; ++i) {
      const int u = tid + 256 * i;
      const int d = u >> 2, cu = u & 3;
      *(uint4*)(&Vls[d][cu * 8]) =
          *(const uint4*)(vb0 + (size_t)d * S_ + kt * 32 + cu * 8);
    }
    __syncthreads();

    f4_t sf[2];
    sf[0] = (f4_t){0.f, 0.f, 0.f, 0.f};
    sf[1] = (f4_t){0.f, 0.f, 0.f, 0.f};
#pragma unroll
    for (int c = 0; c < 8; ++c) {
      const bf8_t b0 = *(const bf8_t*)(&Kls[l15][c * 32 + quad * 8]);
      const bf8_t b1 = *(const bf8_t*)(&Kls[16 + l15][c * 32 + quad * 8]);
      sf[0] = MFMA16(qf[c], b0, sf[0]);
      sf[1] = MFMA16(qf[c], b1, sf[1]);
    }

    const int key0 = kt * 32;
    float mt[4];
#pragma unroll
    for (int r = 0; r < 4; ++r) {
      const int qr = qrow0 + r;
#pragma unroll
      for (int f = 0; f < 2; ++f) {
        const int key = key0 + f * 16 + l15;
        const float sv = sf[f][r] * 0.0625f;
        sf[f][r] = (key <= qr) ? sv : -1e30f;
      }
      mt[r] = fmaxf(sf[0][r], sf[1][r]);
    }
#pragma unroll
    for (int off = 1; off < 16; off <<= 1)
#pragma unroll
      for (int r = 0; r < 4; ++r)
        mt[r] = fmaxf(mt[r], __shfl_xor(mt[r], off));
    float alpha[4], rs[4];
#pragma unroll
    for (int r = 0; r < 4; ++r) {
      const float mn = fmaxf(m_r[r], mt[r]);
      alpha[r] = __expf(m_r[r] - mn);
      m_r[r] = mn;
      const float p0 = __expf(sf[0][r] - mn);
      const float p1 = __expf(sf[1][r] - mn);
      sf[0][r] = p0; sf[1][r] = p1;
      rs[r] = p0 + p1;
    }
#pragma unroll
    for (int off = 1; off < 16; off <<= 1)
#pragma unroll
      for (int r = 0; r < 4; ++r)
        rs[r] += __shfl_xor(rs[r], off);
#pragma unroll
    for (int r = 0; r < 4; ++r)
      l_r[r] = l_r[r] * alpha[r] + rs[r];
#pragma unroll
    for (int i = 0; i < 16; ++i)
#pragma unroll
      for (int r = 0; r < 4; ++r)
        o[i][r] *= alpha[r];

#pragma unroll
    for (int f = 0; f < 2; ++f)
#pragma unroll
      for (int r = 0; r < 4; ++r)
        Pls[wave][quad * 4 + r][f * 16 + l15] = f2bf(sf[f][r]);
    const bf8_t ap = *(const bf8_t*)(&Pls[wave][l15][quad * 8]);

#pragma unroll
    for (int df = 0; df < 16; ++df) {
      const bf8_t bv = *(const bf8_t*)(&Vls[df * 16 + l15][quad * 8]);
      o[df] = MFMA16(ap, bv, o[df]);
    }
  }

  const int b = bh >> 4, h = bh & 15;
  float inv[4];
#pragma unroll
  for (int r = 0; r < 4; ++r) inv[r] = 1.0f / l_r[r];
#pragma unroll
  for (int r = 0; r < 4; ++r) {
    const int s = qt * 64 + wave * 16 + quad * 4 + r;
    ushort* prow = attn + ((size_t)b * S_ + s) * D_ + h * HD_ + l15;
#pragma unroll
    for (int df = 0; df < 16; ++df)
      prow[df * 16] = f2bf(o[df][r] * inv[r]);
  }
}

// ---------------------------------------------------------------------------
extern "C" void kernel_launch(void* const* d_in, const int* in_sizes, int n_in,
                              void* d_out, int out_size, void* d_ws, size_t ws_size,
                              hipStream_t stream)
{
  const float* hid    = (const float*)d_in[0];
  const int*   qw_qkv = (const int*)d_in[1];
  const int*   qz_qkv = (const int*)d_in[2];
  const float* sc_qkv = (const float*)d_in[3];
  const int*   qw_out = (const int*)d_in[4];
  const int*   qz_out = (const int*)d_in[5];
  const float* sc_out = (const float*)d_in[6];
  float* out = (float*)d_out;

  const size_t QKV_E = (size_t)B_ * H_ * S_ * HD_;   // 16,777,216 elems

  if (ws_size >= (size_t)268435456) {
    // fast path: 256 MB layout
    ushort* hidA  = (ushort*)d_ws;          // 33.5 MB (aliased by attn later)
    ushort* wsq   = hidA + QKV_E;
    ushort* wsk   = wsq + QKV_E;
    ushort* wsv   = wsk + QKV_E;
    ushort* wsvt  = wsv + QKV_E;
    ushort* wT    = wsvt + QKV_E;           // 100.7 MB (Wqkv^T, then Wout^T)
    ushort* wsattn = hidA;                  // alias: hidA dead after gemm_fast_qkv

    cvt_bf16<<<dim3(8192), 256, 0, stream>>>(hid, hidA);
    dequant_w<<<dim3(192, 64), 256, 0, stream>>>(qw_qkv, qz_qkv, sc_qkv, wT, N1);
    gemm_fast_qkv<<<dim3(96, 32), 256, 0, stream>>>(hidA, wT, wsq, wsk, wsv);
    rope_qk<<<dim3(16384), 256, 0, stream>>>(wsq, wsk);
    transpose_v<<<dim3(32, 4, 32), 256, 0, stream>>>(wsv, wsvt);
    flash_attn<<<dim3(32, 32), 256, 0, stream>>>(wsq, wsk, wsvt, wsattn);
    dequant_w<<<dim3(64, 64), 256, 0, stream>>>(qw_out, qz_out, sc_out, wT, N2);
    gemm_fast_out<<<dim3(32, 32), 256, 0, stream>>>(wsattn, wT, out);
  } else {
    // fallback: round-1 validated path (168 MB)
    ushort* wsq    = (ushort*)d_ws;
    ushort* wsk    = wsq + QKV_E;
    ushort* wsv    = wsk + QKV_E;
    ushort* wsvt   = wsv + QKV_E;
    ushort* wsattn = wsvt + QKV_E;

    gemm_qkv_fb<<<dim3(96, 32), 256, 0, stream>>>(hid, qw_qkv, qz_qkv, sc_qkv, wsq, wsk, wsv);
    rope_qk<<<dim3(16384), 256, 0, stream>>>(wsq, wsk);
    transpose_v<<<dim3(32, 4, 32), 256, 0, stream>>>(wsv, wsvt);
    flash_attn<<<dim3(32, 32), 256, 0, stream>>>(wsq, wsk, wsvt, wsattn);
    gemm_out_fb<<<dim3(32, 32), 256, 0, stream>>>(wsattn, qw_out, qz_out, sc_out, out);
  }
}

// Round 3
// 956.054 us; speedup vs baseline: 1.5550x; 1.2584x over previous
//
#include <hip/hip_runtime.h>

#define B_  2
#define S_  2048
#define D_  4096
#define H_  16
#define HD_ 256
#define N1  12288
#define N2  4096

typedef __attribute__((ext_vector_type(8))) short  bf8_t;   // 8 bf16 (4 VGPRs)
typedef __attribute__((ext_vector_type(8))) ushort us8_t;
typedef __attribute__((ext_vector_type(4))) float  f4_t;

__device__ __forceinline__ ushort f2bf(float f) {
  union { float f; uint u; } c; c.f = f;
  uint u = c.u;
  return (ushort)((u + 0x7fffu + ((u >> 16) & 1u)) >> 16);  // RNE
}
__device__ __forceinline__ float bf2f(ushort b) {
  union { uint u; float f; } c; c.u = ((uint)b) << 16;
  return c.f;
}

#define MFMA16(a, b, c) __builtin_amdgcn_mfma_f32_16x16x32_bf16((a), (b), (c), 0, 0, 0)

__device__ __forceinline__ void gload16(const void* g, void* l) {
  __builtin_amdgcn_global_load_lds(
      (const __attribute__((address_space(1))) void*)g,
      (__attribute__((address_space(3))) void*)l, 16, 0, 0);
}

// ---------------------------------------------------------------------------
// hidden f32 -> bf16
// ---------------------------------------------------------------------------
__global__ __launch_bounds__(256) void cvt_bf16(const float* __restrict__ x,
                                                ushort* __restrict__ y)
{
  const size_t i = ((size_t)blockIdx.x * 256 + threadIdx.x) * 8;
  const float4 a = *(const float4*)(x + i);
  const float4 b = *(const float4*)(x + i + 4);
  us8_t o;
  o[0] = f2bf(a.x); o[1] = f2bf(a.y); o[2] = f2bf(a.z); o[3] = f2bf(a.w);
  o[4] = f2bf(b.x); o[5] = f2bf(b.y); o[6] = f2bf(b.z); o[7] = f2bf(b.w);
  *(us8_t*)(y + i) = o;
}

// ---------------------------------------------------------------------------
// GPTQ dequant -> W^T bf16 [N][4096]  (one-shot, memory-bound)
// ---------------------------------------------------------------------------
__global__ __launch_bounds__(256) void dequant_w(
    const int* __restrict__ qw, const int* __restrict__ qz,
    const float* __restrict__ sc, ushort* __restrict__ wt, const int N)
{
  __shared__ ushort T[64][72];
  const int tid = threadIdx.x;
  const int n0 = blockIdx.x * 64, k0 = blockIdx.y * 64;
  const int g = k0 >> 7;                           // GS=128
  const int nn  = tid & 63;
  const int kw0 = tid >> 6;                        // 0..3
  const int gn = n0 + nn;
  const int zw = qz[g * (N >> 3) + (gn >> 3)];
  const float zp = (float)(((zw >> ((gn & 7) * 4)) & 15) + 1);
  const float scale = sc[g * N + gn];
  const float szp = scale * zp;
#pragma unroll
  for (int t = 0; t < 2; ++t) {
    const int kw = kw0 + t * 4;
    const uint w = (uint)qw[(size_t)((k0 >> 3) + kw) * N + gn];
    us8_t pk;
#pragma unroll
    for (int j = 0; j < 8; ++j)
      pk[j] = f2bf(fmaf((float)((w >> (4 * j)) & 15u), scale, -szp));
    *(us8_t*)(&T[nn][kw * 8]) = pk;
  }
  __syncthreads();
#pragma unroll
  for (int t = 0; t < 2; ++t) {
    const int u = tid + t * 256;
    const int r = u >> 3, c = u & 7;
    *(uint4*)(wt + (size_t)(n0 + r) * 4096 + k0 + c * 8) = *(uint4*)(&T[r][c * 8]);
  }
}

// ---------------------------------------------------------------------------
// Fast bf16 GEMM core (m97 structure)
// ---------------------------------------------------------------------------
#define GEMM_CORE(A_, BT_)                                                    \
  __shared__ ushort As[8192];                                                 \
  __shared__ ushort Bs[8192];                                                 \
  const int tid  = threadIdx.x;                                               \
  const int lane = tid & 63, wave = tid >> 6;                                 \
  const int quad = lane >> 4, l15 = lane & 15;                                \
  const int n0 = blockIdx.x * 128, m0 = blockIdx.y * 128;                     \
  const int wm = (wave >> 1) * 64, wn = (wave & 1) * 64;                      \
  f4_t acc[4][4];                                                             \
  _Pragma("unroll") for (int i = 0; i < 4; ++i)                               \
  _Pragma("unroll") for (int j = 0; j < 4; ++j)                               \
      acc[i][j] = (f4_t){0.f, 0.f, 0.f, 0.f};                                 \
  const int r_in_c = lane >> 3;                                               \
  const int qc_x   = lane & 7;                                                \
  for (int k0 = 0; k0 < 4096; k0 += 64) {                                     \
    __syncthreads();                                                          \
    _Pragma("unroll") for (int i = 0; i < 4; ++i) {                           \
      const int c = wave * 4 + i;                                             \
      const int row = c * 8 + r_in_c;                                         \
      const int qc  = qc_x ^ (row & 7);                                       \
      gload16(A_ + (size_t)(m0 + row) * 4096 + k0 + qc * 8, &As[c * 512]);    \
      gload16(BT_ + (size_t)(n0 + row) * 4096 + k0 + qc * 8, &Bs[c * 512]);   \
    }                                                                         \
    __syncthreads();                                                          \
    _Pragma("unroll") for (int kk = 0; kk < 2; ++kk) {                        \
      bf8_t af[4], bfv[4];                                                    \
      _Pragma("unroll") for (int i = 0; i < 4; ++i) {                         \
        const int row = wm + i * 16 + l15;                                    \
        const int ch  = (kk * 4 + quad) ^ (row & 7);                          \
        af[i] = *(const bf8_t*)(&As[row * 64 + ch * 8]);                      \
      }                                                                       \
      _Pragma("unroll") for (int j = 0; j < 4; ++j) {                         \
        const int col = wn + j * 16 + l15;                                    \
        const int ch  = (kk * 4 + quad) ^ (col & 7);                          \
        bfv[j] = *(const bf8_t*)(&Bs[col * 64 + ch * 8]);                     \
      }                                                                       \
      _Pragma("unroll") for (int i = 0; i < 4; ++i)                           \
      _Pragma("unroll") for (int j = 0; j < 4; ++j)                           \
          acc[i][j] = MFMA16(af[i], bfv[j], acc[i][j]);                       \
    }                                                                         \
  }

__global__ __launch_bounds__(256) void gemm_fast_qkv(
    const ushort* __restrict__ A, const ushort* __restrict__ BT,
    ushort* __restrict__ wq, ushort* __restrict__ wk, ushort* __restrict__ wv)
{
  GEMM_CORE(A, BT)
  // epilogue: scatter to (which, B, H, S, hd) bf16; q prescaled by 1/sqrt(hd)
  const int which = n0 >> 12;
  const int nh = (n0 & 4095) >> 8;
  const int d0 = n0 & 255;
  const int bb = m0 >> 11;
  const int s_base = m0 & 2047;
  ushort* dst = (which == 0) ? wq : (which == 1) ? wk : wv;
  const float osc = (which == 0) ? 0.0625f : 1.0f;
  const size_t rowbase = ((size_t)bb * H_ + nh) * S_;
#pragma unroll
  for (int i = 0; i < 4; ++i) {
#pragma unroll
    for (int r = 0; r < 4; ++r) {
      const int s = s_base + wm + i * 16 + quad * 4 + r;
      ushort* prow = dst + (rowbase + s) * HD_ + d0 + wn + l15;
#pragma unroll
      for (int j = 0; j < 4; ++j)
        prow[j * 16] = f2bf(acc[i][j][r] * osc);
    }
  }
}

__global__ __launch_bounds__(256) void gemm_fast_out(
    const ushort* __restrict__ A, const ushort* __restrict__ BT,
    float* __restrict__ out)
{
  GEMM_CORE(A, BT)
#pragma unroll
  for (int i = 0; i < 4; ++i) {
#pragma unroll
    for (int r = 0; r < 4; ++r) {
      float* prow = out + (size_t)(m0 + wm + i * 16 + quad * 4 + r) * D_ + n0 + wn + l15;
#pragma unroll
      for (int j = 0; j < 4; ++j)
        prow[j * 16] = acc[i][j][r];
    }
  }
}

// ---------------------------------------------------------------------------
// RoPE in-place on q and k (q is prescaled; rotation commutes with scalar)
// ---------------------------------------------------------------------------
__global__ __launch_bounds__(256) void rope_qk(ushort* __restrict__ q, ushort* __restrict__ k)
{
  const int idx = blockIdx.x * 256 + threadIdx.x;
  const int i   = idx & 31;
  const int row = (idx >> 5) & 0xFFFF;
  const int buf = idx >> 21;
  const int s   = row & 2047;
  ushort* p = (buf ? k : q) + (size_t)row * HD_ + 2 * i;
  const float inv_freq = expf((float)(2 * i) * -0.14391157f);
  const float ang = (float)s * inv_freq;
  float sn, cs;
  sincosf(ang, &sn, &cs);
  uint pr = *(uint*)p;
  const float x1 = bf2f((ushort)(pr & 0xFFFF));
  const float x2 = bf2f((ushort)(pr >> 16));
  const uint lo = f2bf(x1 * cs - x2 * sn);
  const uint hi = f2bf(x2 * cs + x1 * sn);
  *(uint*)p = lo | (hi << 16);
}

// ---------------------------------------------------------------------------
// V (B,H,S,hd) -> VT (B,H,hd,S)
// ---------------------------------------------------------------------------
__global__ __launch_bounds__(256) void transpose_v(const ushort* __restrict__ v,
                                                   ushort* __restrict__ vt)
{
  __shared__ uint t32[64][65];
  const int tid = threadIdx.x;
  const int s0 = blockIdx.x * 64, d0 = blockIdx.y * 64, bh = blockIdx.z;
  const ushort* src = v + ((size_t)bh * S_ + s0) * HD_ + d0;
#pragma unroll
  for (int i = 0; i < 2; ++i) {
    const int u = tid + 256 * i;
    const int r = u >> 3, cu = u & 7;
    const uint4 val = *(const uint4*)(src + (size_t)r * HD_ + cu * 8);
    const ushort* pv = (const ushort*)&val;
#pragma unroll
    for (int j = 0; j < 8; ++j) t32[r][cu * 8 + j] = pv[j];
  }
  __syncthreads();
  ushort* dstb = vt + ((size_t)bh * HD_ + d0) * S_ + s0;
#pragma unroll
  for (int i = 0; i < 2; ++i) {
    const int u = tid + 256 * i;
    const int dr = u >> 3, cu = u & 7;
    union { ushort u16[8]; uint4 v4; } tmp;
#pragma unroll
    for (int j = 0; j < 8; ++j) tmp.u16[j] = (ushort)t32[cu * 8 + j][dr];
    *(uint4*)(dstb + (size_t)dr * S_ + cu * 8) = tmp.v4;
  }
}

// ---------------------------------------------------------------------------
// Flash attention v2: ones-column l, rescale-skip, swizzled global_load_lds K
// Q is prescaled by 1/sqrt(hd). Grid: (bh, qtile) with qtile heavy-first.
// ---------------------------------------------------------------------------
__global__ __launch_bounds__(256) void flash_attn2(
    const ushort* __restrict__ Q, const ushort* __restrict__ K,
    const ushort* __restrict__ VT, ushort* __restrict__ attn)
{
  __shared__ ushort Kls[8192];         // 32 keys x 256 c, 16B-chunk swizzled
  __shared__ ushort Vls[256][40];      // [d][key] +8 pad
  __shared__ ushort Pls[4][16][40];    // per-wave P roundtrip
  const int tid  = threadIdx.x;
  const int lane = tid & 63, wave = tid >> 6;
  const int quad = lane >> 4, l15 = lane & 15;
  const int bh = blockIdx.x;
  const int qt = 31 - blockIdx.y;      // heavy blocks dispatched first

  const ushort* qb = Q + ((size_t)bh * S_ + qt * 64 + wave * 16 + l15) * HD_;
  bf8_t qf[8];
#pragma unroll
  for (int c = 0; c < 8; ++c)
    qf[c] = *(const bf8_t*)(qb + c * 32 + quad * 8);

  bf8_t onef;
#pragma unroll
  for (int j = 0; j < 8; ++j) onef[j] = (short)0x3f80;   // 1.0 bf16

  f4_t o[16];
#pragma unroll
  for (int i = 0; i < 16; ++i) o[i] = (f4_t){0.f, 0.f, 0.f, 0.f};
  f4_t ol = (f4_t){0.f, 0.f, 0.f, 0.f};                 // l accumulator
  float m_r[4] = {-1e30f, -1e30f, -1e30f, -1e30f};

  const int qrow0 = qt * 64 + wave * 16 + quad * 4;
  const int wave_min_row = qt * 64 + wave * 16;
  const int nkt = 2 * (qt + 1);
  const ushort* kb0 = K + (size_t)bh * S_ * HD_;
  const ushort* vb0 = VT + (size_t)bh * HD_ * S_;

  // staging indices (K): chunk c covers rows c*2..c*2+1 (512B each)
  const int st_row_off = lane >> 5;    // 0/1
  const int st_u = lane & 31;

  for (int kt = 0; kt < nkt; ++kt) {
    const int key0 = kt * 32;
    __syncthreads();
    // K: global_load_lds, 16B-chunk XOR swizzle in the GLOBAL address
#pragma unroll
    for (int i = 0; i < 4; ++i) {
      const int c = wave * 4 + i;
      const int row = c * 2 + st_row_off;
      const int g = st_u ^ (row & 7);
      gload16(kb0 + (size_t)(key0 + row) * HD_ + g * 8, &Kls[c * 512]);
    }
    // V: VGPR roundtrip staging
#pragma unroll
    for (int i = 0; i < 4; ++i) {
      const int u = tid + 256 * i;
      const int d = u >> 2, cu = u & 3;
      *(uint4*)(&Vls[d][cu * 8]) =
          *(const uint4*)(vb0 + (size_t)d * S_ + key0 + cu * 8);
    }
    __syncthreads();

    // S = Q K^T : 16 x 32 (swizzled Kls reads)
    f4_t sf0 = (f4_t){0.f, 0.f, 0.f, 0.f};
    f4_t sf1 = (f4_t){0.f, 0.f, 0.f, 0.f};
    const int sx = l15 & 7;
#pragma unroll
    for (int cc = 0; cc < 8; ++cc) {
      const int w = cc * 4 + quad;
      const bf8_t b0 = *(const bf8_t*)(&Kls[l15 * 256 + (w ^ sx) * 8]);
      const bf8_t b1 = *(const bf8_t*)(&Kls[(16 + l15) * 256 + (w ^ sx) * 8]);
      sf0 = MFMA16(qf[cc], b0, sf0);
      sf1 = MFMA16(qf[cc], b1, sf1);
    }

    // mask (only when tile crosses the diagonal for this wave)
    float mt[4];
    if (key0 + 31 <= wave_min_row) {
#pragma unroll
      for (int r = 0; r < 4; ++r) mt[r] = fmaxf(sf0[r], sf1[r]);
    } else {
#pragma unroll
      for (int r = 0; r < 4; ++r) {
        const int qr = qrow0 + r;
        sf0[r] = (key0 + l15 <= qr)      ? sf0[r] : -1e30f;
        sf1[r] = (key0 + 16 + l15 <= qr) ? sf1[r] : -1e30f;
        mt[r] = fmaxf(sf0[r], sf1[r]);
      }
    }
#pragma unroll
    for (int off = 1; off < 16; off <<= 1)
#pragma unroll
      for (int r = 0; r < 4; ++r)
        mt[r] = fmaxf(mt[r], __shfl_xor(mt[r], off));

    // rescale only when the running max grew (rare)
    const bool chg = (mt[0] > m_r[0]) | (mt[1] > m_r[1]) |
                     (mt[2] > m_r[2]) | (mt[3] > m_r[3]);
    if (__any(chg)) {
      float alpha[4];
#pragma unroll
      for (int r = 0; r < 4; ++r) {
        const float mn = fmaxf(m_r[r], mt[r]);
        alpha[r] = __expf(m_r[r] - mn);
        m_r[r] = mn;
      }
#pragma unroll
      for (int i = 0; i < 16; ++i)
#pragma unroll
        for (int r = 0; r < 4; ++r)
          o[i][r] *= alpha[r];
#pragma unroll
      for (int r = 0; r < 4; ++r) ol[r] *= alpha[r];
    }
#pragma unroll
    for (int r = 0; r < 4; ++r) {
      sf0[r] = __expf(sf0[r] - m_r[r]);
      sf1[r] = __expf(sf1[r] - m_r[r]);
    }

    // P (C-layout) -> LDS -> A-layout; wave-private
#pragma unroll
    for (int r = 0; r < 4; ++r) {
      Pls[wave][quad * 4 + r][l15]      = f2bf(sf0[r]);
      Pls[wave][quad * 4 + r][16 + l15] = f2bf(sf1[r]);
    }
    const bf8_t ap = *(const bf8_t*)(&Pls[wave][l15][quad * 8]);

    // O += P V ; l += P 1
    ol = MFMA16(ap, onef, ol);
#pragma unroll
    for (int df = 0; df < 16; ++df) {
      const bf8_t bv = *(const bf8_t*)(&Vls[df * 16 + l15][quad * 8]);
      o[df] = MFMA16(ap, bv, o[df]);
    }
  }

  // epilogue: attn (B,S,D) bf16
  const int b = bh >> 4, h = bh & 15;
  float inv[4];
#pragma unroll
  for (int r = 0; r < 4; ++r) inv[r] = 1.0f / ol[r];
#pragma unroll
  for (int r = 0; r < 4; ++r) {
    const int s = qt * 64 + wave * 16 + quad * 4 + r;
    ushort* prow = attn + ((size_t)b * S_ + s) * D_ + h * HD_ + l15;
#pragma unroll
    for (int df = 0; df < 16; ++df)
      prow[df * 16] = f2bf(o[df][r] * inv[r]);
  }
}

// ---------------------------------------------------------------------------
// FALLBACK (dequant-in-GEMM), used only if ws < 256 MiB
// ---------------------------------------------------------------------------
__global__ __launch_bounds__(256) void gemm_qkv_fb(
    const float* __restrict__ hid, const int* __restrict__ qw,
    const int* __restrict__ qz, const float* __restrict__ sc,
    ushort* __restrict__ wq, ushort* __restrict__ wk, ushort* __restrict__ wv)
{
  __shared__ ushort As[128][72];
  __shared__ ushort Bs[128][72];
  const int tid  = threadIdx.x;
  const int lane = tid & 63, wave = tid >> 6;
  const int quad = lane >> 4, l15 = lane & 15;
  const int n0 = blockIdx.x * 128, m0 = blockIdx.y * 128;
  f4_t acc[4][4];
#pragma unroll
  for (int i = 0; i < 4; ++i)
#pragma unroll
    for (int j = 0; j < 4; ++j) acc[i][j] = (f4_t){0.f, 0.f, 0.f, 0.f};
  const int bn  = tid & 127;
  const int brh = tid >> 7;
  const int gn  = n0 + bn;
  const int wm = (wave >> 1) * 64, wn = (wave & 1) * 64;
  for (int k0 = 0; k0 < D_; k0 += 64) {
#pragma unroll
    for (int i = 0; i < 8; ++i) {
      const int u = tid + 256 * i;
      const int m = u >> 4, kc = u & 15;
      const float4 v = *(const float4*)(hid + (size_t)(m0 + m) * D_ + k0 + kc * 4);
      ushort4 b;
      b.x = f2bf(v.x); b.y = f2bf(v.y); b.z = f2bf(v.z); b.w = f2bf(v.w);
      *(ushort4*)(&As[m][kc * 4]) = b;
    }
    {
      const int g = k0 >> 7;
      const int zw = qz[g * (N1 / 8) + (gn >> 3)];
      const float zp = (float)(((zw >> ((gn & 7) * 4)) & 15) + 1);
      const float scale = sc[g * N1 + gn];
      const float szp = scale * zp;
      const int kq0 = (k0 >> 3) + brh * 4;
#pragma unroll
      for (int i = 0; i < 4; ++i) {
        const uint w = (uint)qw[(size_t)(kq0 + i) * N1 + gn];
        us8_t pk;
#pragma unroll
        for (int j = 0; j < 8; ++j)
          pk[j] = f2bf(fmaf((float)((w >> (4 * j)) & 15u), scale, -szp));
        *(us8_t*)(&Bs[bn][(brh * 4 + i) * 8]) = pk;
      }
    }
    __syncthreads();
#pragma unroll
    for (int kk = 0; kk < 64; kk += 32) {
      bf8_t af[4], bfv[4];
#pragma unroll
      for (int i = 0; i < 4; ++i)
        af[i] = *(const bf8_t*)(&As[wm + i * 16 + l15][kk + quad * 8]);
#pragma unroll
      for (int j = 0; j < 4; ++j)
        bfv[j] = *(const bf8_t*)(&Bs[wn + j * 16 + l15][kk + quad * 8]);
#pragma unroll
      for (int i = 0; i < 4; ++i)
#pragma unroll
        for (int j = 0; j < 4; ++j)
          acc[i][j] = MFMA16(af[i], bfv[j], acc[i][j]);
    }
    __syncthreads();
  }
  const int which = n0 >> 12;
  const int nh = (n0 & 4095) >> 8;
  const int d0 = n0 & 255;
  const int bb = m0 >> 11;
  const int s_base = m0 & 2047;
  ushort* dst = (which == 0) ? wq : (which == 1) ? wk : wv;
  const float osc = (which == 0) ? 0.0625f : 1.0f;
  const size_t rowbase = ((size_t)bb * H_ + nh) * S_;
#pragma unroll
  for (int i = 0; i < 4; ++i) {
#pragma unroll
    for (int r = 0; r < 4; ++r) {
      const int s = s_base + wm + i * 16 + quad * 4 + r;
      ushort* prow = dst + (rowbase + s) * HD_ + d0 + wn + l15;
#pragma unroll
      for (int j = 0; j < 4; ++j)
        prow[j * 16] = f2bf(acc[i][j][r] * osc);
    }
  }
}

__global__ __launch_bounds__(256) void gemm_out_fb(
    const ushort* __restrict__ attn, const int* __restrict__ qw,
    const int* __restrict__ qz, const float* __restrict__ sc,
    float* __restrict__ out)
{
  __shared__ ushort As[128][72];
  __shared__ ushort Bs[128][72];
  const int tid  = threadIdx.x;
  const int lane = tid & 63, wave = tid >> 6;
  const int quad = lane >> 4, l15 = lane & 15;
  const int n0 = blockIdx.x * 128, m0 = blockIdx.y * 128;
  f4_t acc[4][4];
#pragma unroll
  for (int i = 0; i < 4; ++i)
#pragma unroll
    for (int j = 0; j < 4; ++j) acc[i][j] = (f4_t){0.f, 0.f, 0.f, 0.f};
  const int bn  = tid & 127;
  const int brh = tid >> 7;
  const int gn  = n0 + bn;
  const int wm = (wave >> 1) * 64, wn = (wave & 1) * 64;
  for (int k0 = 0; k0 < D_; k0 += 64) {
#pragma unroll
    for (int i = 0; i < 4; ++i) {
      const int u = tid + 256 * i;
      const int m = u >> 3, kc = u & 7;
      *(uint4*)(&As[m][kc * 8]) =
          *(const uint4*)(attn + (size_t)(m0 + m) * D_ + k0 + kc * 8);
    }
    {
      const int g = k0 >> 7;
      const int zw = qz[g * (N2 / 8) + (gn >> 3)];
      const float zp = (float)(((zw >> ((gn & 7) * 4)) & 15) + 1);
      const float scale = sc[g * N2 + gn];
      const float szp = scale * zp;
      const int kq0 = (k0 >> 3) + brh * 4;
#pragma unroll
      for (int i = 0; i < 4; ++i) {
        const uint w = (uint)qw[(size_t)(kq0 + i) * N2 + gn];
        us8_t pk;
#pragma unroll
        for (int j = 0; j < 8; ++j)
          pk[j] = f2bf(fmaf((float)((w >> (4 * j)) & 15u), scale, -szp));
        *(us8_t*)(&Bs[bn][(brh * 4 + i) * 8]) = pk;
      }
    }
    __syncthreads();
#pragma unroll
    for (int kk = 0; kk < 64; kk += 32) {
      bf8_t af[4], bfv[4];
#pragma unroll
      for (int i = 0; i < 4; ++i)
        af[i] = *(const bf8_t*)(&As[wm + i * 16 + l15][kk + quad * 8]);
#pragma unroll
      for (int j = 0; j < 4; ++j)
        bfv[j] = *(const bf8_t*)(&Bs[wn + j * 16 + l15][kk + quad * 8]);
#pragma unroll
      for (int i = 0; i < 4; ++i)
#pragma unroll
        for (int j = 0; j < 4; ++j)
          acc[i][j] = MFMA16(af[i], bfv[j], acc[i][j]);
    }
    __syncthreads();
  }
#pragma unroll
  for (int i = 0; i < 4; ++i) {
#pragma unroll
    for (int r = 0; r < 4; ++r) {
      float* prow = out + (size_t)(m0 + wm + i * 16 + quad * 4 + r) * D_ + n0 + wn + l15;
#pragma unroll
      for (int j = 0; j < 4; ++j)
        prow[j * 16] = acc[i][j][r];
    }
  }
}

// ---------------------------------------------------------------------------
extern "C" void kernel_launch(void* const* d_in, const int* in_sizes, int n_in,
                              void* d_out, int out_size, void* d_ws, size_t ws_size,
                              hipStream_t stream)
{
  const float* hid    = (const float*)d_in[0];
  const int*   qw_qkv = (const int*)d_in[1];
  const int*   qz_qkv = (const int*)d_in[2];
  const float* sc_qkv = (const float*)d_in[3];
  const int*   qw_out = (const int*)d_in[4];
  const int*   qz_out = (const int*)d_in[5];
  const float* sc_out = (const float*)d_in[6];
  float* out = (float*)d_out;

  const size_t QKV_E = (size_t)B_ * H_ * S_ * HD_;   // 16,777,216 elems

  if (ws_size >= (size_t)268435456) {
    // fast path: exactly 256 MiB layout
    ushort* hidA  = (ushort*)d_ws;          // 33.5 MB (aliased by attn later)
    ushort* wsq   = hidA + QKV_E;
    ushort* wsk   = wsq + QKV_E;
    ushort* wsv   = wsk + QKV_E;
    ushort* wsvt  = wsv + QKV_E;
    ushort* wT    = wsvt + QKV_E;           // 100.7 MB (Wqkv^T, then Wout^T)
    ushort* wsattn = hidA;                  // alias: hidA dead after gemm_fast_qkv

    cvt_bf16<<<dim3(8192), 256, 0, stream>>>(hid, hidA);
    dequant_w<<<dim3(192, 64), 256, 0, stream>>>(qw_qkv, qz_qkv, sc_qkv, wT, N1);
    gemm_fast_qkv<<<dim3(96, 32), 256, 0, stream>>>(hidA, wT, wsq, wsk, wsv);
    rope_qk<<<dim3(16384), 256, 0, stream>>>(wsq, wsk);
    transpose_v<<<dim3(32, 4, 32), 256, 0, stream>>>(wsv, wsvt);
    flash_attn2<<<dim3(32, 32), 256, 0, stream>>>(wsq, wsk, wsvt, wsattn);
    dequant_w<<<dim3(64, 64), 256, 0, stream>>>(qw_out, qz_out, sc_out, wT, N2);
    gemm_fast_out<<<dim3(32, 32), 256, 0, stream>>>(wsattn, wT, out);
  } else {
    // fallback path (168 MB)
    ushort* wsq    = (ushort*)d_ws;
    ushort* wsk    = wsq + QKV_E;
    ushort* wsv    = wsk + QKV_E;
    ushort* wsvt   = wsv + QKV_E;
    ushort* wsattn = wsvt + QKV_E;

    gemm_qkv_fb<<<dim3(96, 32), 256, 0, stream>>>(hid, qw_qkv, qz_qkv, sc_qkv, wsq, wsk, wsv);
    rope_qk<<<dim3(16384), 256, 0, stream>>>(wsq, wsk);
    transpose_v<<<dim3(32, 4, 32), 256, 0, stream>>>(wsv, wsvt);
    flash_attn2<<<dim3(32, 32), 256, 0, stream>>>(wsq, wsk, wsvt, wsattn);
    gemm_out_fb<<<dim3(32, 32), 256, 0, stream>>>(wsattn, qw_out, qz_out, sc_out, out);
  }
}